// Round 3
// baseline (161.237 us; speedup 1.0000x reference)
//
#include <hip/hip_runtime.h>

#define B_SZ   4096
#define H_SZ   200
#define D_SZ   128
#define N_SZ   256
#define ROWS   (B_SZ * H_SZ)      // 819200
#define BM     64
#define TPB    8                  // tiles per block
#define RPB    (BM * TPB)         // 512 rows per block
#define NBLK   (ROWS / RPB)       // 1600

typedef __attribute__((ext_vector_type(8))) short bf16x8;
typedef __attribute__((ext_vector_type(4))) float f32x4;

__device__ __forceinline__ unsigned short f2bf(float f) {
    unsigned u = __builtin_bit_cast(unsigned, f);
    u += 0x7FFFu + ((u >> 16) & 1u);
    return (unsigned short)(u >> 16);
}
__device__ __forceinline__ float bflo(unsigned d) {
    return __builtin_bit_cast(float, d << 16);
}
__device__ __forceinline__ float bfhi(unsigned d) {
    return __builtin_bit_cast(float, d & 0xFFFF0000u);
}
__device__ __forceinline__ unsigned packtr(float a, float b) {
    return (__builtin_bit_cast(unsigned, a) >> 16) |
           (__builtin_bit_cast(unsigned, b) & 0xFFFF0000u);
}

// Kernel 0: embed_history f32 -> bf16 (RNE)
__global__ __launch_bounds__(256) void cvt_eh(const float* __restrict__ src,
                                              uint4* __restrict__ dst, int n8) {
    int i = blockIdx.x * 256 + threadIdx.x;
    if (i >= n8) return;
    const f32x4* p = (const f32x4*)src + (size_t)i * 2;
    f32x4 a = p[0], b = p[1];
    uint4 o;
    o.x = (unsigned)f2bf(a[0]) | ((unsigned)f2bf(a[1]) << 16);
    o.y = (unsigned)f2bf(a[2]) | ((unsigned)f2bf(a[3]) << 16);
    o.z = (unsigned)f2bf(b[0]) | ((unsigned)f2bf(b[1]) << 16);
    o.w = (unsigned)f2bf(b[2]) | ((unsigned)f2bf(b[3]) << 16);
    dst[i] = o;
}

// Main: 512 thr = 8 waves; wave w owns N-cols [32w,32w+32).
// Construct thread (row=tid>>3, seg=tid&7) covers d in [8s,8s+8) u [64+8s,64+8s+8).
__global__ __launch_bounds__(512, 6) void nais_main(
    const int* __restrict__ history, const int* __restrict__ target,
    const uint4* __restrict__ eh16, const float* __restrict__ et,
    const float* __restrict__ W1, const float* __restrict__ b1,
    const float* __restrict__ w2,
    float* __restrict__ a_out, float* __restrict__ dotd_out)
{
    __shared__ uint4 AbufV[BM * 256 / 16];     // 16 KB swizzled [64][128] bf16
    __shared__ float apart[8][BM];             // 2 KB
    __shared__ float tgt_p[4][16][12];         // 3 KB padded chunks (conflict-free)
    __shared__ int   tgt_i[4];
    char* Abuf = (char*)AbufV;

    const int tid  = threadIdx.x;
    const int wid  = tid >> 6;
    const int lane = tid & 63;
    const int lo   = lane & 15;
    const int hi   = lane >> 4;
    const int row  = tid >> 3;
    const int seg  = tid & 7;
    const int blk  = blockIdx.x;
    const int b_base = (blk * RPB) / H_SZ;

    if (tid < 4) {
        int bb = b_base + tid;
        tgt_i[tid] = target[bb < B_SZ ? bb : (B_SZ - 1)];
    }
    __syncthreads();
    {   // preload 4 target rows into padded chunks: tgt_p[r][c][e] = et[b_r][8c+e]
        const int r4 = tid >> 7, d = tid & 127;
        tgt_p[r4][d >> 3][d & 7] = et[(size_t)tgt_i[r4] * D_SZ + d];
    }

    // W1 B-fragments: wave wid owns cols [32*wid, 32*wid+32)
    bf16x8 wfrag[4][2];
    float  b1v[2], w2v[2];
    #pragma unroll
    for (int ni = 0; ni < 2; ++ni) {
        int n = 32 * wid + 16 * ni + lo;
        b1v[ni] = b1[n];
        w2v[ni] = w2[n];
        #pragma unroll
        for (int ki = 0; ki < 4; ++ki) {
            bf16x8 f;
            #pragma unroll
            for (int e = 0; e < 8; ++e)
                f[e] = (short)f2bf(W1[(32 * ki + 8 * hi + e) * N_SZ + n]);
            wfrag[ki][ni] = f;
        }
    }

    // gather pipeline prologue
    const int grow0 = blk * RPB + row;
    const int* hrow = history + grow0;
    int ih_cur = hrow[0];
    int ih_nxt = hrow[BM];
    uint4 hq0, hq1;
    {
        const uint4* p = eh16 + (size_t)ih_cur * 16;
        hq0 = p[seg]; hq1 = p[8 + seg];
    }
    __syncthreads();   // tgt_p ready

    for (int t = 0; t < TPB; ++t) {
        const int gr    = grow0 + t * BM;              // this thread's global row
        const int b_loc = gr / H_SZ - b_base;          // 0..3

        // ---- construct ----
        const float* tA = &tgt_p[b_loc][seg][0];
        const float* tB = &tgt_p[b_loc][8 + seg][0];
        f32x4 ta0 = *(const f32x4*)tA, ta1 = *(const f32x4*)(tA + 4);
        f32x4 tb0 = *(const f32x4*)tB, tb1 = *(const f32x4*)(tB + 4);
        float tAv[8] = {ta0[0], ta0[1], ta0[2], ta0[3], ta1[0], ta1[1], ta1[2], ta1[3]};
        float tBv[8] = {tb0[0], tb0[1], tb0[2], tb0[3], tb1[0], tb1[1], tb1[2], tb1[3]};
        unsigned h1[4] = {hq0.x, hq0.y, hq0.z, hq0.w};
        unsigned h2[4] = {hq1.x, hq1.y, hq1.z, hq1.w};
        unsigned xp1[4], xp2[4];
        float s = 0.f;
        #pragma unroll
        for (int j = 0; j < 4; ++j) {
            float x0 = bflo(h1[j]) * tAv[2 * j];
            float x1 = bfhi(h1[j]) * tAv[2 * j + 1];
            float y0 = bflo(h2[j]) * tBv[2 * j];
            float y1 = bfhi(h2[j]) * tBv[2 * j + 1];
            s += (x0 + x1) + (y0 + y1);
            xp1[j] = packtr(x0, x1);
            xp2[j] = packtr(y0, y1);
        }
        s += __shfl_xor(s, 1);
        s += __shfl_xor(s, 2);
        s += __shfl_xor(s, 4);
        if (seg == 0) dotd_out[gr] = s;
        {
            const unsigned sw = (unsigned)((row & 7) << 4);
            char* rb = Abuf + row * 256;
            *(uint4*)(rb + (((unsigned)(16 * seg)) ^ sw))       = uint4{xp1[0], xp1[1], xp1[2], xp1[3]};
            *(uint4*)(rb + (128u + (((unsigned)(16 * seg)) ^ sw))) = uint4{xp2[0], xp2[1], xp2[2], xp2[3]};
        }
        __syncthreads();   // [B1] A-tile ready

        // ---- prefetch next tile's gathers ----
        if (t + 1 < TPB) {
            ih_cur = ih_nxt;
            if (t + 2 < TPB) ih_nxt = hrow[(t + 2) * BM];
            const uint4* p = eh16 + (size_t)ih_cur * 16;
            hq0 = p[seg]; hq1 = p[8 + seg];
        }

        // ---- MFMA + per-mi epilogue ----
        #pragma unroll
        for (int mi = 0; mi < 4; ++mi) {
            const int rr = 16 * mi + lo;
            const unsigned swr = (unsigned)((rr & 7) << 4);
            bf16x8 af[4];
            #pragma unroll
            for (int ki = 0; ki < 4; ++ki) {
                unsigned off = ((unsigned)(64 * ki + 16 * hi)) ^ swr;
                af[ki] = *(const bf16x8*)(Abuf + rr * 256 + off);
            }
            f32x4 acc0 = {0.f, 0.f, 0.f, 0.f};
            f32x4 acc1 = {0.f, 0.f, 0.f, 0.f};
            #pragma unroll
            for (int ki = 0; ki < 4; ++ki) {
                acc0 = __builtin_amdgcn_mfma_f32_16x16x32_bf16(af[ki], wfrag[ki][0], acc0, 0, 0, 0);
                acc1 = __builtin_amdgcn_mfma_f32_16x16x32_bf16(af[ki], wfrag[ki][1], acc1, 0, 0, 0);
            }
            // fold: v[reg] = relu(acc0+b1)*w2 + relu(acc1+b1)*w2
            float v0 = fmaxf(acc0[0] + b1v[0], 0.f) * w2v[0] + fmaxf(acc1[0] + b1v[1], 0.f) * w2v[1];
            float v1 = fmaxf(acc0[1] + b1v[0], 0.f) * w2v[0] + fmaxf(acc1[1] + b1v[1], 0.f) * w2v[1];
            float v2 = fmaxf(acc0[2] + b1v[0], 0.f) * w2v[0] + fmaxf(acc1[2] + b1v[1], 0.f) * w2v[1];
            float v3 = fmaxf(acc0[3] + b1v[0], 0.f) * w2v[0] + fmaxf(acc1[3] + b1v[1], 0.f) * w2v[1];
            // value-combining tree over 16 lanes: lane ends with v[lane&3]
            const bool up1 = lane & 1, up2 = lane & 2;
            float k01 = up1 ? v1 : v0, s01 = up1 ? v0 : v1;
            float a01 = k01 + __shfl_xor(s01, 1);
            float k23 = up1 ? v3 : v2, s23 = up1 ? v2 : v3;
            float a23 = k23 + __shfl_xor(s23, 1);
            float kk  = up2 ? a23 : a01, ss = up2 ? a01 : a23;
            float r   = kk + __shfl_xor(ss, 2);
            r += __shfl_xor(r, 4);
            r += __shfl_xor(r, 8);
            if (lo < 4) apart[wid][16 * mi + 4 * hi + lo] = r;
        }
        __syncthreads();   // [B2] apart ready; Abuf reads done

        if (tid < BM) {
            float a = apart[0][tid];
            #pragma unroll
            for (int w = 1; w < 8; ++w) a += apart[w][tid];
            a_out[blk * RPB + t * BM + tid] = a;
        }
    }
}

// Finish: per-b masked exp, beta=0.5 power norm, weighted dot, sigmoid
__global__ __launch_bounds__(64) void nais_finish(
    const int* __restrict__ history, const int* __restrict__ target,
    const float* __restrict__ a_in, const float* __restrict__ dotd_in,
    float* __restrict__ out)
{
    const int b    = blockIdx.x;
    const int lane = threadIdx.x;
    const int tgt  = target[b];
    float s1 = 0.f, s2 = 0.f;
    for (int h = lane; h < H_SZ; h += 64) {
        int rg = b * H_SZ + h;
        float e = (history[rg] != tgt) ? __expf(a_in[rg]) : 0.f;
        s1 += e;
        s2 += e * dotd_in[rg];
    }
    #pragma unroll
    for (int o = 1; o < 64; o <<= 1) {
        s1 += __shfl_xor(s1, o);
        s2 += __shfl_xor(s2, o);
    }
    if (lane == 0) {
        float pred = s2 / sqrtf(s1);
        out[b] = 1.f / (1.f + __expf(-pred));
    }
}

extern "C" void kernel_launch(void* const* d_in, const int* in_sizes, int n_in,
                              void* d_out, int out_size, void* d_ws, size_t ws_size,
                              hipStream_t stream) {
    const int*   history = (const int*)d_in[0];
    const int*   target  = (const int*)d_in[1];
    const float* eh      = (const float*)d_in[2];
    const float* et      = (const float*)d_in[3];
    const float* W1      = (const float*)d_in[4];
    const float* b1      = (const float*)d_in[5];
    const float* w2      = (const float*)d_in[6];
    float* out = (float*)d_out;

    uint4* eh16   = (uint4*)d_ws;                              // 25.6 MB
    float* a_ws   = (float*)((char*)d_ws + (size_t)100000 * D_SZ * 2);
    float* dotd_ws = a_ws + ROWS;                              // +3.3 MB each

    const int n8 = 100000 * D_SZ / 8;
    cvt_eh<<<(n8 + 255) / 256, 256, 0, stream>>>(eh, eh16, n8);
    nais_main<<<NBLK, 512, 0, stream>>>(history, target, eh16, et, W1, b1, w2, a_ws, dotd_ws);
    nais_finish<<<B_SZ, 64, 0, stream>>>(history, target, a_ws, dotd_ws, out);
}

// Round 4
// 109.853 us; speedup vs baseline: 1.4678x; 1.4678x over previous
//
#include <hip/hip_runtime.h>

#define B_SZ   4096
#define H_SZ   200
#define D_SZ   128
#define N_SZ   256
#define ROWS   (B_SZ * H_SZ)      // 819200
#define BM     64
#define TPB    8                  // tiles per block
#define RPB    (BM * TPB)         // 512 rows per block
#define NBLK   (ROWS / RPB)       // 1600

typedef __attribute__((ext_vector_type(8))) short bf16x8;
typedef __attribute__((ext_vector_type(4))) float f32x4;

__device__ __forceinline__ unsigned short f2bf(float f) {
    unsigned u = __builtin_bit_cast(unsigned, f);
    u += 0x7FFFu + ((u >> 16) & 1u);
    return (unsigned short)(u >> 16);
}
__device__ __forceinline__ float bflo(unsigned d) {
    return __builtin_bit_cast(float, d << 16);
}
__device__ __forceinline__ float bfhi(unsigned d) {
    return __builtin_bit_cast(float, d & 0xFFFF0000u);
}
__device__ __forceinline__ unsigned packtr(float a, float b) {
    return (__builtin_bit_cast(unsigned, a) >> 16) |
           (__builtin_bit_cast(unsigned, b) & 0xFFFF0000u);
}

// Kernel 0a: embed_history f32 -> bf16 (RNE)
__global__ __launch_bounds__(256) void cvt_eh(const float* __restrict__ src,
                                              uint4* __restrict__ dst, int n8) {
    int i = blockIdx.x * 256 + threadIdx.x;
    if (i >= n8) return;
    const f32x4* p = (const f32x4*)src + (size_t)i * 2;
    f32x4 a = p[0], b = p[1];
    uint4 o;
    o.x = (unsigned)f2bf(a[0]) | ((unsigned)f2bf(a[1]) << 16);
    o.y = (unsigned)f2bf(a[2]) | ((unsigned)f2bf(a[3]) << 16);
    o.z = (unsigned)f2bf(b[0]) | ((unsigned)f2bf(b[1]) << 16);
    o.w = (unsigned)f2bf(b[2]) | ((unsigned)f2bf(b[3]) << 16);
    dst[i] = o;
}

// Kernel 0b: W1 [128][256] f32 -> W1T [256][128] bf16
__global__ __launch_bounds__(256) void cvt_w1(const float* __restrict__ src,
                                              unsigned short* __restrict__ dst) {
    int i = blockIdx.x * 256 + threadIdx.x;   // i = n*128 + d
    int n = i >> 7, d = i & 127;
    dst[i] = f2bf(src[d * N_SZ + n]);
}

// Main: 512 thr = 8 waves; wave w owns N-cols [32w,32w+32).
// Double-buffered A-tile, ONE barrier per tile, lagged apart reduction.
__global__ __launch_bounds__(512, 4) void nais_main(
    const int* __restrict__ history, const int* __restrict__ target,
    const uint4* __restrict__ eh16, const float* __restrict__ et,
    const unsigned short* __restrict__ w1t, const float* __restrict__ b1,
    const float* __restrict__ w2,
    float* __restrict__ a_out, float* __restrict__ dotd_out)
{
    __shared__ uint4 AbufV[2][BM * 256 / 16];  // 32 KB swizzled [64][128] bf16 x2
    __shared__ float apart[2][8][BM];          // 4 KB
    __shared__ float tgt_p[4][16][12];         // 3 KB padded chunks
    __shared__ int   tgt_i[4];

    const int tid  = threadIdx.x;
    const int wid  = tid >> 6;
    const int lane = tid & 63;
    const int lo   = lane & 15;
    const int hi   = lane >> 4;
    const int row  = tid >> 3;
    const int seg  = tid & 7;
    const int blk  = blockIdx.x;
    const int b_base = (blk * RPB) / H_SZ;

    if (tid < 4) {
        int bb = b_base + tid;
        tgt_i[tid] = target[bb < B_SZ ? bb : (B_SZ - 1)];
    }
    __syncthreads();
    {   // preload up to 4 target rows: tgt_p[r][c][e] = et[b_r][8c+e]
        const int r4 = tid >> 7, d = tid & 127;
        tgt_p[r4][d >> 3][d & 7] = et[(size_t)tgt_i[r4] * D_SZ + d];
    }

    // W1T B-fragments (vectorized): wave wid owns cols [32*wid, 32*wid+32)
    bf16x8 wfrag[4][2];
    float  b1v[2], w2v[2];
    #pragma unroll
    for (int ni = 0; ni < 2; ++ni) {
        int n = 32 * wid + 16 * ni + lo;
        b1v[ni] = b1[n];
        w2v[ni] = w2[n];
        #pragma unroll
        for (int ki = 0; ki < 4; ++ki)
            wfrag[ki][ni] = *(const bf16x8*)(w1t + (size_t)n * D_SZ + 32 * ki + 8 * hi);
    }

    // gather pipeline prologue
    const int grow0 = blk * RPB + row;
    const int* hrow = history + grow0;
    int ih_nxt = hrow[BM];
    uint4 hq0, hq1;
    {
        const uint4* p = eh16 + (size_t)hrow[0] * 16;
        hq0 = p[seg]; hq1 = p[8 + seg];
    }
    __syncthreads();   // tgt_p ready

    for (int t = 0; t < TPB; ++t) {
        char* Ab = (char*)AbufV[t & 1];
        const int gr    = grow0 + t * BM;
        const int b_loc = gr / H_SZ - b_base;   // 0..3

        // ---- construct tile t into Ab (from prefetched hq regs) ----
        {
            const float* tA = &tgt_p[b_loc][seg][0];
            const float* tB = &tgt_p[b_loc][8 + seg][0];
            f32x4 ta0 = *(const f32x4*)tA, ta1 = *(const f32x4*)(tA + 4);
            f32x4 tb0 = *(const f32x4*)tB, tb1 = *(const f32x4*)(tB + 4);
            float tAv[8] = {ta0[0], ta0[1], ta0[2], ta0[3], ta1[0], ta1[1], ta1[2], ta1[3]};
            float tBv[8] = {tb0[0], tb0[1], tb0[2], tb0[3], tb1[0], tb1[1], tb1[2], tb1[3]};
            unsigned h1[4] = {hq0.x, hq0.y, hq0.z, hq0.w};
            unsigned h2[4] = {hq1.x, hq1.y, hq1.z, hq1.w};
            unsigned xp1[4], xp2[4];
            float s = 0.f;
            #pragma unroll
            for (int j = 0; j < 4; ++j) {
                float x0 = bflo(h1[j]) * tAv[2 * j];
                float x1 = bfhi(h1[j]) * tAv[2 * j + 1];
                float y0 = bflo(h2[j]) * tBv[2 * j];
                float y1 = bfhi(h2[j]) * tBv[2 * j + 1];
                s += (x0 + x1) + (y0 + y1);
                xp1[j] = packtr(x0, x1);
                xp2[j] = packtr(y0, y1);
            }
            s += __shfl_xor(s, 1);
            s += __shfl_xor(s, 2);
            s += __shfl_xor(s, 4);
            if (seg == 0) dotd_out[gr] = s;
            const unsigned sw = (unsigned)((row & 7) << 4);
            char* rb = Ab + row * 256;
            *(uint4*)(rb + (((unsigned)(16 * seg)) ^ sw))          = uint4{xp1[0], xp1[1], xp1[2], xp1[3]};
            *(uint4*)(rb + (128u + (((unsigned)(16 * seg)) ^ sw))) = uint4{xp2[0], xp2[1], xp2[2], xp2[3]};
        }
        __syncthreads();   // [single barrier per tile]

        // ---- prefetch next tile's gathers (hides under MFMA) ----
        if (t + 1 < TPB) {
            int ih_cur = ih_nxt;
            if (t + 2 < TPB) ih_nxt = hrow[(t + 2) * BM];
            const uint4* p = eh16 + (size_t)ih_cur * 16;
            hq0 = p[seg]; hq1 = p[8 + seg];
        }

        // ---- lagged reduction of tile t-1's apart ----
        if (t > 0 && tid < BM) {
            const float* ap = &apart[(t - 1) & 1][0][tid];
            float a = ap[0];
            #pragma unroll
            for (int w = 1; w < 8; ++w) a += ap[w * BM];
            a_out[blk * RPB + (t - 1) * BM + tid] = a;
        }

        // ---- MFMA + per-mi epilogue ----
        #pragma unroll
        for (int mi = 0; mi < 4; ++mi) {
            const int rr = 16 * mi + lo;
            const unsigned swr = (unsigned)((rr & 7) << 4);
            bf16x8 af[4];
            #pragma unroll
            for (int ki = 0; ki < 4; ++ki) {
                unsigned off = ((unsigned)(64 * ki + 16 * hi)) ^ swr;
                af[ki] = *(const bf16x8*)(Ab + rr * 256 + off);
            }
            f32x4 acc0 = {0.f, 0.f, 0.f, 0.f};
            f32x4 acc1 = {0.f, 0.f, 0.f, 0.f};
            __builtin_amdgcn_s_setprio(1);
            #pragma unroll
            for (int ki = 0; ki < 4; ++ki) {
                acc0 = __builtin_amdgcn_mfma_f32_16x16x32_bf16(af[ki], wfrag[ki][0], acc0, 0, 0, 0);
                acc1 = __builtin_amdgcn_mfma_f32_16x16x32_bf16(af[ki], wfrag[ki][1], acc1, 0, 0, 0);
            }
            __builtin_amdgcn_s_setprio(0);
            float v0 = fmaxf(acc0[0] + b1v[0], 0.f) * w2v[0] + fmaxf(acc1[0] + b1v[1], 0.f) * w2v[1];
            float v1 = fmaxf(acc0[1] + b1v[0], 0.f) * w2v[0] + fmaxf(acc1[1] + b1v[1], 0.f) * w2v[1];
            float v2 = fmaxf(acc0[2] + b1v[0], 0.f) * w2v[0] + fmaxf(acc1[2] + b1v[1], 0.f) * w2v[1];
            float v3 = fmaxf(acc0[3] + b1v[0], 0.f) * w2v[0] + fmaxf(acc1[3] + b1v[1], 0.f) * w2v[1];
            const bool up1 = lane & 1, up2 = lane & 2;
            float k01 = up1 ? v1 : v0, s01 = up1 ? v0 : v1;
            float a01 = k01 + __shfl_xor(s01, 1);
            float k23 = up1 ? v3 : v2, s23 = up1 ? v2 : v3;
            float a23 = k23 + __shfl_xor(s23, 1);
            float kk  = up2 ? a23 : a01, ss = up2 ? a01 : a23;
            float r   = kk + __shfl_xor(ss, 2);
            r += __shfl_xor(r, 4);
            r += __shfl_xor(r, 8);
            if (lo < 4) apart[t & 1][wid][16 * mi + 4 * hi + lo] = r;
        }
    }
    __syncthreads();
    if (tid < BM) {   // final tile's reduction
        const float* ap = &apart[(TPB - 1) & 1][0][tid];
        float a = ap[0];
        #pragma unroll
        for (int w = 1; w < 8; ++w) a += ap[w * BM];
        a_out[blk * RPB + (TPB - 1) * BM + tid] = a;
    }
}

// Finish: per-b masked exp, beta=0.5 power norm, weighted dot, sigmoid
__global__ __launch_bounds__(64) void nais_finish(
    const int* __restrict__ history, const int* __restrict__ target,
    const float* __restrict__ a_in, const float* __restrict__ dotd_in,
    float* __restrict__ out)
{
    const int b    = blockIdx.x;
    const int lane = threadIdx.x;
    const int tgt  = target[b];
    float s1 = 0.f, s2 = 0.f;
    for (int h = lane; h < H_SZ; h += 64) {
        int rg = b * H_SZ + h;
        float e = (history[rg] != tgt) ? __expf(a_in[rg]) : 0.f;
        s1 += e;
        s2 += e * dotd_in[rg];
    }
    #pragma unroll
    for (int o = 1; o < 64; o <<= 1) {
        s1 += __shfl_xor(s1, o);
        s2 += __shfl_xor(s2, o);
    }
    if (lane == 0) {
        float pred = s2 / sqrtf(s1);
        out[b] = 1.f / (1.f + __expf(-pred));
    }
}

extern "C" void kernel_launch(void* const* d_in, const int* in_sizes, int n_in,
                              void* d_out, int out_size, void* d_ws, size_t ws_size,
                              hipStream_t stream) {
    const int*   history = (const int*)d_in[0];
    const int*   target  = (const int*)d_in[1];
    const float* eh      = (const float*)d_in[2];
    const float* et      = (const float*)d_in[3];
    const float* W1      = (const float*)d_in[4];
    const float* b1      = (const float*)d_in[5];
    const float* w2      = (const float*)d_in[6];
    float* out = (float*)d_out;

    char* ws = (char*)d_ws;
    uint4*          eh16 = (uint4*)ws;                           // 25.6 MB
    unsigned short* w1t  = (unsigned short*)(ws + (size_t)100000 * D_SZ * 2);  // 64 KB
    float*          a_ws = (float*)(ws + (size_t)100000 * D_SZ * 2 + N_SZ * D_SZ * 2);
    float*          dotd_ws = a_ws + ROWS;

    const int n8 = 100000 * D_SZ / 8;
    cvt_eh<<<(n8 + 255) / 256, 256, 0, stream>>>(eh, eh16, n8);
    cvt_w1<<<(N_SZ * D_SZ) / 256, 256, 0, stream>>>(W1, w1t);
    nais_main<<<NBLK, 512, 0, stream>>>(history, target, eh16, et, w1t, b1, w2, a_ws, dotd_ws);
    nais_finish<<<B_SZ, 64, 0, stream>>>(history, target, a_ws, dotd_ws, out);
}

// Round 5
// 101.497 us; speedup vs baseline: 1.5886x; 1.0823x over previous
//
#include <hip/hip_runtime.h>

#define B_SZ   4096
#define H_SZ   200
#define D_SZ   128
#define N_SZ   256
#define ROWS   (B_SZ * H_SZ)      // 819200
#define BM     64
#define TPB    8                  // tiles per block
#define RPB    (BM * TPB)         // 512 rows per block
#define NBLK   (ROWS / RPB)       // 1600

typedef __attribute__((ext_vector_type(8))) short bf16x8;
typedef __attribute__((ext_vector_type(4))) float f32x4;

__device__ __forceinline__ unsigned short f2bf(float f) {
    unsigned u = __builtin_bit_cast(unsigned, f);
    u += 0x7FFFu + ((u >> 16) & 1u);
    return (unsigned short)(u >> 16);
}
__device__ __forceinline__ float bflo(unsigned d) {
    return __builtin_bit_cast(float, d << 16);
}
__device__ __forceinline__ float bfhi(unsigned d) {
    return __builtin_bit_cast(float, d & 0xFFFF0000u);
}
__device__ __forceinline__ unsigned packtr(float a, float b) {
    return (__builtin_bit_cast(unsigned, a) >> 16) |
           (__builtin_bit_cast(unsigned, b) & 0xFFFF0000u);
}

// Kernel 0a: embed_history f32 -> bf16 (RNE)
__global__ __launch_bounds__(256) void cvt_eh(const float* __restrict__ src,
                                              uint4* __restrict__ dst, int n8) {
    int i = blockIdx.x * 256 + threadIdx.x;
    if (i >= n8) return;
    const f32x4* p = (const f32x4*)src + (size_t)i * 2;
    f32x4 a = p[0], b = p[1];
    uint4 o;
    o.x = (unsigned)f2bf(a[0]) | ((unsigned)f2bf(a[1]) << 16);
    o.y = (unsigned)f2bf(a[2]) | ((unsigned)f2bf(a[3]) << 16);
    o.z = (unsigned)f2bf(b[0]) | ((unsigned)f2bf(b[1]) << 16);
    o.w = (unsigned)f2bf(b[2]) | ((unsigned)f2bf(b[3]) << 16);
    dst[i] = o;
}

// Kernel 0b: W1 [128][256] f32 -> W1T [256][128] bf16
__global__ __launch_bounds__(256) void cvt_w1(const float* __restrict__ src,
                                              unsigned short* __restrict__ dst) {
    int i = blockIdx.x * 256 + threadIdx.x;   // i = n*128 + d
    int n = i >> 7, d = i & 127;
    dst[i] = f2bf(src[d * N_SZ + n]);
}

// Main: 512 thr = 8 waves; wave w owns N-cols [32w,32w+32).
// SWAPPED MFMA: mfma(wfrag, af) -> lane lo = x-row, regs = N-cols.
// b1 folded into accumulator init; epilogue = fmax+fma + 2 shuffles.
__global__ __launch_bounds__(512, 4) void nais_main(
    const int* __restrict__ history, const int* __restrict__ target,
    const uint4* __restrict__ eh16, const float* __restrict__ et,
    const unsigned short* __restrict__ w1t, const float* __restrict__ b1,
    const float* __restrict__ w2,
    float* __restrict__ a_out, float* __restrict__ dotd_out)
{
    __shared__ uint4 AbufV[2][BM * 256 / 16];  // 32 KB swizzled [64][128] bf16 x2
    __shared__ float apart[2][8][BM];          // 4 KB
    __shared__ float tgt_p[4][16][12];         // 3 KB padded chunks
    __shared__ int   tgt_i[4];

    const int tid  = threadIdx.x;
    const int wid  = tid >> 6;
    const int lane = tid & 63;
    const int lo   = lane & 15;
    const int hi   = lane >> 4;
    const int row  = tid >> 3;
    const int seg  = tid & 7;
    const int blk  = blockIdx.x;
    const int b_base = (blk * RPB) / H_SZ;

    if (tid < 4) {
        int bb = b_base + tid;
        tgt_i[tid] = target[bb < B_SZ ? bb : (B_SZ - 1)];
    }
    __syncthreads();
    {   // preload up to 4 target rows: tgt_p[r][c][e] = et[b_r][8c+e]
        const int r4 = tid >> 7, d = tid & 127;
        tgt_p[r4][d >> 3][d & 7] = et[(size_t)tgt_i[r4] * D_SZ + d];
    }

    // W1T fragments (A-operand of the swapped MFMA): wave wid owns cols [32wid, 32wid+32)
    bf16x8 wfrag[4][2];
    #pragma unroll
    for (int ni = 0; ni < 2; ++ni) {
        int n = 32 * wid + 16 * ni + lo;
        #pragma unroll
        for (int ki = 0; ki < 4; ++ki)
            wfrag[ki][ni] = *(const bf16x8*)(w1t + (size_t)n * D_SZ + 32 * ki + 8 * hi);
    }
    // b1 / w2 per-lane: n = 32wid + {0,16} + 4hi + r  (vectorized f32x4)
    const int n0 = 32 * wid + 4 * hi;
    const f32x4 b1a = *(const f32x4*)(b1 + n0);
    const f32x4 b1b = *(const f32x4*)(b1 + n0 + 16);
    const f32x4 w2a = *(const f32x4*)(w2 + n0);
    const f32x4 w2b = *(const f32x4*)(w2 + n0 + 16);

    // gather pipeline prologue
    const int grow0 = blk * RPB + row;
    const int* hrow = history + grow0;
    int ih_nxt = hrow[BM];
    uint4 hq0, hq1;
    {
        const uint4* p = eh16 + (size_t)hrow[0] * 16;
        hq0 = p[seg]; hq1 = p[8 + seg];
    }
    __syncthreads();   // tgt_p ready

    for (int t = 0; t < TPB; ++t) {
        char* Ab = (char*)AbufV[t & 1];
        const int gr    = grow0 + t * BM;
        const int b_loc = gr / H_SZ - b_base;   // 0..3

        // ---- construct tile t into Ab (from prefetched hq regs) ----
        {
            const float* tA = &tgt_p[b_loc][seg][0];
            const float* tB = &tgt_p[b_loc][8 + seg][0];
            f32x4 ta0 = *(const f32x4*)tA, ta1 = *(const f32x4*)(tA + 4);
            f32x4 tb0 = *(const f32x4*)tB, tb1 = *(const f32x4*)(tB + 4);
            float tAv[8] = {ta0[0], ta0[1], ta0[2], ta0[3], ta1[0], ta1[1], ta1[2], ta1[3]};
            float tBv[8] = {tb0[0], tb0[1], tb0[2], tb0[3], tb1[0], tb1[1], tb1[2], tb1[3]};
            unsigned h1[4] = {hq0.x, hq0.y, hq0.z, hq0.w};
            unsigned h2[4] = {hq1.x, hq1.y, hq1.z, hq1.w};
            unsigned xp1[4], xp2[4];
            float s = 0.f;
            #pragma unroll
            for (int j = 0; j < 4; ++j) {
                float x0 = bflo(h1[j]) * tAv[2 * j];
                float x1 = bfhi(h1[j]) * tAv[2 * j + 1];
                float y0 = bflo(h2[j]) * tBv[2 * j];
                float y1 = bfhi(h2[j]) * tBv[2 * j + 1];
                s += (x0 + x1) + (y0 + y1);
                xp1[j] = packtr(x0, x1);
                xp2[j] = packtr(y0, y1);
            }
            s += __shfl_xor(s, 1);
            s += __shfl_xor(s, 2);
            s += __shfl_xor(s, 4);
            if (seg == 0) dotd_out[gr] = s;
            const unsigned sw = (unsigned)((row & 7) << 4);
            char* rb = Ab + row * 256;
            *(uint4*)(rb + (((unsigned)(16 * seg)) ^ sw))          = uint4{xp1[0], xp1[1], xp1[2], xp1[3]};
            *(uint4*)(rb + (128u + (((unsigned)(16 * seg)) ^ sw))) = uint4{xp2[0], xp2[1], xp2[2], xp2[3]};
        }
        __syncthreads();   // [single barrier per tile]

        // ---- prefetch next tile's gathers (hides under MFMA) ----
        if (t + 1 < TPB) {
            int ih_cur = ih_nxt;
            if (t + 2 < TPB) ih_nxt = hrow[(t + 2) * BM];
            const uint4* p = eh16 + (size_t)ih_cur * 16;
            hq0 = p[seg]; hq1 = p[8 + seg];
        }

        // ---- lagged reduction of tile t-1's apart ----
        if (t > 0 && tid < BM) {
            const float* ap = &apart[(t - 1) & 1][0][tid];
            float a = ap[0];
            #pragma unroll
            for (int w = 1; w < 8; ++w) a += ap[w * BM];
            a_out[blk * RPB + (t - 1) * BM + tid] = a;
        }

        // ---- swapped MFMA + cheap epilogue ----
        #pragma unroll
        for (int mi = 0; mi < 4; ++mi) {
            const int rr = 16 * mi + lo;
            const unsigned swr = (unsigned)((rr & 7) << 4);
            bf16x8 af[4];
            #pragma unroll
            for (int ki = 0; ki < 4; ++ki) {
                unsigned off = ((unsigned)(64 * ki + 16 * hi)) ^ swr;
                af[ki] = *(const bf16x8*)(Ab + rr * 256 + off);
            }
            f32x4 acc0 = b1a;   // b1 folded into accumulator init
            f32x4 acc1 = b1b;
            __builtin_amdgcn_s_setprio(1);
            #pragma unroll
            for (int ki = 0; ki < 4; ++ki) {
                acc0 = __builtin_amdgcn_mfma_f32_16x16x32_bf16(wfrag[ki][0], af[ki], acc0, 0, 0, 0);
                acc1 = __builtin_amdgcn_mfma_f32_16x16x32_bf16(wfrag[ki][1], af[ki], acc1, 0, 0, 0);
            }
            __builtin_amdgcn_s_setprio(0);
            // lane lo = x-row (16mi+lo); regs = N-cols {n0+r, n0+16+r}
            float v = fmaxf(acc0[0], 0.f) * w2a[0] + fmaxf(acc1[0], 0.f) * w2b[0];
            v += fmaxf(acc0[1], 0.f) * w2a[1] + fmaxf(acc1[1], 0.f) * w2b[1];
            v += fmaxf(acc0[2], 0.f) * w2a[2] + fmaxf(acc1[2], 0.f) * w2b[2];
            v += fmaxf(acc0[3], 0.f) * w2a[3] + fmaxf(acc1[3], 0.f) * w2b[3];
            v += __shfl_xor(v, 16);
            v += __shfl_xor(v, 32);
            if (lane < 16) apart[t & 1][wid][16 * mi + lane] = v;
        }
    }
    __syncthreads();
    if (tid < BM) {   // final tile's reduction
        const float* ap = &apart[(TPB - 1) & 1][0][tid];
        float a = ap[0];
        #pragma unroll
        for (int w = 1; w < 8; ++w) a += ap[w * BM];
        a_out[blk * RPB + (TPB - 1) * BM + tid] = a;
    }
}

// Finish: per-b masked exp, beta=0.5 power norm, weighted dot, sigmoid
__global__ __launch_bounds__(64) void nais_finish(
    const int* __restrict__ history, const int* __restrict__ target,
    const float* __restrict__ a_in, const float* __restrict__ dotd_in,
    float* __restrict__ out)
{
    const int b    = blockIdx.x;
    const int lane = threadIdx.x;
    const int tgt  = target[b];
    float s1 = 0.f, s2 = 0.f;
    for (int h = lane; h < H_SZ; h += 64) {
        int rg = b * H_SZ + h;
        float e = (history[rg] != tgt) ? __expf(a_in[rg]) : 0.f;
        s1 += e;
        s2 += e * dotd_in[rg];
    }
    #pragma unroll
    for (int o = 1; o < 64; o <<= 1) {
        s1 += __shfl_xor(s1, o);
        s2 += __shfl_xor(s2, o);
    }
    if (lane == 0) {
        float pred = s2 / sqrtf(s1);
        out[b] = 1.f / (1.f + __expf(-pred));
    }
}

extern "C" void kernel_launch(void* const* d_in, const int* in_sizes, int n_in,
                              void* d_out, int out_size, void* d_ws, size_t ws_size,
                              hipStream_t stream) {
    const int*   history = (const int*)d_in[0];
    const int*   target  = (const int*)d_in[1];
    const float* eh      = (const float*)d_in[2];
    const float* et      = (const float*)d_in[3];
    const float* W1      = (const float*)d_in[4];
    const float* b1      = (const float*)d_in[5];
    const float* w2      = (const float*)d_in[6];
    float* out = (float*)d_out;

    char* ws = (char*)d_ws;
    uint4*          eh16 = (uint4*)ws;                           // 25.6 MB
    unsigned short* w1t  = (unsigned short*)(ws + (size_t)100000 * D_SZ * 2);  // 64 KB
    float*          a_ws = (float*)(ws + (size_t)100000 * D_SZ * 2 + N_SZ * D_SZ * 2);
    float*          dotd_ws = a_ws + ROWS;

    const int n8 = 100000 * D_SZ / 8;
    cvt_eh<<<(n8 + 255) / 256, 256, 0, stream>>>(eh, eh16, n8);
    cvt_w1<<<(N_SZ * D_SZ) / 256, 256, 0, stream>>>(W1, w1t);
    nais_main<<<NBLK, 512, 0, stream>>>(history, target, eh16, et, w1t, b1, w2, a_ws, dotd_ws);
    nais_finish<<<B_SZ, 64, 0, stream>>>(history, target, a_ws, dotd_ws, out);
}

// Round 7
// 98.759 us; speedup vs baseline: 1.6326x; 1.0277x over previous
//
#include <hip/hip_runtime.h>

#define B_SZ   4096
#define H_SZ   200
#define D_SZ   128
#define N_SZ   256
#define ROWS   (B_SZ * H_SZ)      // 819200
#define BM     64
#define TPB    8                  // tiles per block
#define RPB    (BM * TPB)         // 512 rows per block
#define NBLK   (ROWS / RPB)       // 1600

typedef _Float16 f16;
typedef __attribute__((ext_vector_type(2))) _Float16 f16x2;
typedef __attribute__((ext_vector_type(8))) _Float16 f16x8;
typedef __attribute__((ext_vector_type(4))) float f32x4;

union H8 { f16x8 v; f16x2 p[4]; uint4 u; };

__device__ __forceinline__ f16x2 pkrtz(float a, float b) {
    return __builtin_bit_cast(f16x2, __builtin_amdgcn_cvt_pkrtz(a, b));
}

// Kernel 0a: embed_history f32 -> f16 (RTZ pack), 8 elems/thread
__global__ __launch_bounds__(256) void cvt_eh(const float* __restrict__ src,
                                              uint4* __restrict__ dst, int n8) {
    int i = blockIdx.x * 256 + threadIdx.x;
    if (i >= n8) return;
    const f32x4* p = (const f32x4*)src + (size_t)i * 2;
    f32x4 a = p[0], b = p[1];
    uint4 o;
    o.x = __builtin_bit_cast(unsigned, pkrtz(a[0], a[1]));
    o.y = __builtin_bit_cast(unsigned, pkrtz(a[2], a[3]));
    o.z = __builtin_bit_cast(unsigned, pkrtz(b[0], b[1]));
    o.w = __builtin_bit_cast(unsigned, pkrtz(b[2], b[3]));
    dst[i] = o;
}

// Kernel 0b: W1 [128][256] f32 -> W1T/16 [256][128] f16
__global__ __launch_bounds__(256) void cvt_w1(const float* __restrict__ src,
                                              f16* __restrict__ dst) {
    int i = blockIdx.x * 256 + threadIdx.x;   // i = n*128 + d
    int n = i >> 7, d = i & 127;
    dst[i] = (f16)(src[d * N_SZ + n] * 0.0625f);
}

// Main: 512 thr = 8 waves; wave w owns N-cols [32w,32w+32).
// f16 datapath: pk_mul construct, fdot2 dotd, f16 MFMA (swapped operands).
// Scaling: t stored x16, W1 stored /16 -> pre-activation exact; dotd /16 at write.
__global__ __launch_bounds__(512, 4) void nais_main(
    const int* __restrict__ history, const int* __restrict__ target,
    const uint4* __restrict__ ehh, const float* __restrict__ et,
    const f16* __restrict__ w1t, const float* __restrict__ b1,
    const float* __restrict__ w2,
    float* __restrict__ a_out, float* __restrict__ dotd_out)
{
    __shared__ uint4 AbufV[2][BM * 256 / 16];  // 32 KB swizzled [64][128] f16 x2
    __shared__ float apart[2][8][BM];          // 4 KB
    __shared__ f16   tgt_h[4][D_SZ];           // 1 KB (t * 16, f16)
    __shared__ int   tgt_i[4];

    const int tid  = threadIdx.x;
    const int wid  = tid >> 6;
    const int lane = tid & 63;
    const int lo   = lane & 15;
    const int hi   = lane >> 4;
    const int row  = tid >> 3;
    const int seg  = tid & 7;
    const int blk  = blockIdx.x;
    const int b_base = (blk * RPB) / H_SZ;

    if (tid < 4) {
        int bb = b_base + tid;
        tgt_i[tid] = target[bb < B_SZ ? bb : (B_SZ - 1)];
    }
    __syncthreads();
    if (tid < 256) {   // preload 4 target rows as f16 * 16
        const int r4 = tid >> 6, j = (tid & 63) * 2;
        const float* src = et + (size_t)tgt_i[r4] * D_SZ + j;
        ((f16x2*)tgt_h)[tid] = pkrtz(src[0] * 16.f, src[1] * 16.f);
    }

    // W1T/16 fragments (A-operand of swapped MFMA): wave wid owns cols [32wid, 32wid+32)
    f16x8 wfrag[4][2];
    #pragma unroll
    for (int ni = 0; ni < 2; ++ni) {
        int n = 32 * wid + 16 * ni + lo;
        #pragma unroll
        for (int ki = 0; ki < 4; ++ki)
            wfrag[ki][ni] = *(const f16x8*)(w1t + (size_t)n * D_SZ + 32 * ki + 8 * hi);
    }
    // b1 / w2 per-lane: n = 32wid + {0,16} + 4hi + r
    const int n0 = 32 * wid + 4 * hi;
    const f32x4 b1a = *(const f32x4*)(b1 + n0);
    const f32x4 b1b = *(const f32x4*)(b1 + n0 + 16);
    const f32x4 w2a = *(const f32x4*)(w2 + n0);
    const f32x4 w2b = *(const f32x4*)(w2 + n0 + 16);

    // gather pipeline prologue
    const int grow0 = blk * RPB + row;
    const int* hrow = history + grow0;
    int ih_cur = hrow[0];
    int ih_nxt = hrow[BM];
    uint4 hq0, hq1;
    {
        const uint4* p = ehh + (size_t)ih_cur * 16;
        hq0 = p[seg]; hq1 = p[8 + seg];
    }
    // incremental b_loc (avoid per-tile integer divide)
    int b_loc = grow0 / H_SZ - b_base;
    int rem   = grow0 - (b_loc + b_base) * H_SZ;
    __syncthreads();   // tgt_h ready

    for (int t = 0; t < TPB; ++t) {
        char* Ab = (char*)AbufV[t & 1];
        const int gr = grow0 + t * BM;

        // ---- construct tile t (f16 packed) ----
        {
            H8 h1, h2, t1, t2, x1, x2;
            h1.u = hq0; h2.u = hq1;
            t1.v = *(const f16x8*)&tgt_h[b_loc][8 * seg];
            t2.v = *(const f16x8*)&tgt_h[b_loc][64 + 8 * seg];
            x1.v = h1.v * t1.v;        // 16*x, f16 packed
            x2.v = h2.v * t2.v;
            float s = 0.f;
            #pragma unroll
            for (int j = 0; j < 4; ++j) {
                s = __builtin_amdgcn_fdot2(h1.p[j], t1.p[j], s, false);
                s = __builtin_amdgcn_fdot2(h2.p[j], t2.p[j], s, false);
            }
            s += __shfl_xor(s, 1);
            s += __shfl_xor(s, 2);
            s += __shfl_xor(s, 4);
            if (seg == 0) dotd_out[gr] = s * 0.0625f;
            const unsigned sw = (unsigned)((row & 7) << 4);
            char* rb = Ab + row * 256;
            *(uint4*)(rb + (((unsigned)(16 * seg)) ^ sw))          = x1.u;
            *(uint4*)(rb + (128u + (((unsigned)(16 * seg)) ^ sw))) = x2.u;
        }
        __syncthreads();   // [single barrier per tile]

        // ---- prefetch next tile's gathers (hides under MFMA) ----
        if (t + 1 < TPB) {
            ih_cur = ih_nxt;
            if (t + 2 < TPB) ih_nxt = hrow[(t + 2) * BM];
            const uint4* p = ehh + (size_t)ih_cur * 16;
            hq0 = p[seg]; hq1 = p[8 + seg];
        }

        // ---- lagged reduction of tile t-1's apart ----
        if (t > 0 && tid < BM) {
            const float* ap = &apart[(t - 1) & 1][0][tid];
            float a = ap[0];
            #pragma unroll
            for (int w = 1; w < 8; ++w) a += ap[w * BM];
            a_out[blk * RPB + (t - 1) * BM + tid] = a;
        }

        // ---- swapped MFMA + cheap epilogue ----
        #pragma unroll
        for (int mi = 0; mi < 4; ++mi) {
            const int rr = 16 * mi + lo;
            const unsigned swr = (unsigned)((rr & 7) << 4);
            f16x8 af[4];
            #pragma unroll
            for (int ki = 0; ki < 4; ++ki) {
                unsigned off = ((unsigned)(64 * ki + 16 * hi)) ^ swr;
                af[ki] = *(const f16x8*)(Ab + rr * 256 + off);
            }
            f32x4 acc0 = b1a;   // b1 folded into accumulator init
            f32x4 acc1 = b1b;
            __builtin_amdgcn_s_setprio(1);
            #pragma unroll
            for (int ki = 0; ki < 4; ++ki) {
                acc0 = __builtin_amdgcn_mfma_f32_16x16x32_f16(wfrag[ki][0], af[ki], acc0, 0, 0, 0);
                acc1 = __builtin_amdgcn_mfma_f32_16x16x32_f16(wfrag[ki][1], af[ki], acc1, 0, 0, 0);
            }
            __builtin_amdgcn_s_setprio(0);
            // lane lo = x-row (16mi+lo); regs = N-cols {n0+r, n0+16+r}
            float v = fmaxf(acc0[0], 0.f) * w2a[0] + fmaxf(acc1[0], 0.f) * w2b[0];
            v += fmaxf(acc0[1], 0.f) * w2a[1] + fmaxf(acc1[1], 0.f) * w2b[1];
            v += fmaxf(acc0[2], 0.f) * w2a[2] + fmaxf(acc1[2], 0.f) * w2b[2];
            v += fmaxf(acc0[3], 0.f) * w2a[3] + fmaxf(acc1[3], 0.f) * w2b[3];
            v += __shfl_xor(v, 16);
            v += __shfl_xor(v, 32);
            if (lane < 16) apart[t & 1][wid][16 * mi + lane] = v;
        }

        // advance incremental b_loc for next tile (row += 64)
        rem += BM;
        if (rem >= H_SZ) { rem -= H_SZ; ++b_loc; }
    }
    __syncthreads();
    if (tid < BM) {   // final tile's reduction
        const float* ap = &apart[(TPB - 1) & 1][0][tid];
        float a = ap[0];
        #pragma unroll
        for (int w = 1; w < 8; ++w) a += ap[w * BM];
        a_out[blk * RPB + (TPB - 1) * BM + tid] = a;
    }
}

// Finish: per-b masked exp, beta=0.5 power norm, weighted dot, sigmoid
__global__ __launch_bounds__(64) void nais_finish(
    const int* __restrict__ history, const int* __restrict__ target,
    const float* __restrict__ a_in, const float* __restrict__ dotd_in,
    float* __restrict__ out)
{
    const int b    = blockIdx.x;
    const int lane = threadIdx.x;
    const int tgt  = target[b];
    float s1 = 0.f, s2 = 0.f;
    for (int h = lane; h < H_SZ; h += 64) {
        int rg = b * H_SZ + h;
        float e = (history[rg] != tgt) ? __expf(a_in[rg]) : 0.f;
        s1 += e;
        s2 += e * dotd_in[rg];
    }
    #pragma unroll
    for (int o = 1; o < 64; o <<= 1) {
        s1 += __shfl_xor(s1, o);
        s2 += __shfl_xor(s2, o);
    }
    if (lane == 0) {
        float pred = s2 / sqrtf(s1);
        out[b] = 1.f / (1.f + __expf(-pred));
    }
}

extern "C" void kernel_launch(void* const* d_in, const int* in_sizes, int n_in,
                              void* d_out, int out_size, void* d_ws, size_t ws_size,
                              hipStream_t stream) {
    const int*   history = (const int*)d_in[0];
    const int*   target  = (const int*)d_in[1];
    const float* eh      = (const float*)d_in[2];
    const float* et      = (const float*)d_in[3];
    const float* W1      = (const float*)d_in[4];
    const float* b1      = (const float*)d_in[5];
    const float* w2      = (const float*)d_in[6];
    float* out = (float*)d_out;

    char* ws = (char*)d_ws;
    uint4* ehh = (uint4*)ws;                                     // 25.6 MB (f16)
    f16*   w1t = (f16*)(ws + (size_t)100000 * D_SZ * 2);         // 64 KB
    float* a_ws = (float*)(ws + (size_t)100000 * D_SZ * 2 + N_SZ * D_SZ * 2);
    float* dotd_ws = a_ws + ROWS;

    const int n8 = 100000 * D_SZ / 8;
    cvt_eh<<<(n8 + 255) / 256, 256, 0, stream>>>(eh, ehh, n8);
    cvt_w1<<<(N_SZ * D_SZ) / 256, 256, 0, stream>>>(W1, w1t);
    nais_main<<<NBLK, 512, 0, stream>>>(history, target, ehh, et, w1t, b1, w2, a_ws, dotd_ws);
    nais_finish<<<B_SZ, 64, 0, stream>>>(history, target, a_ws, dotd_ws, out);
}